// Round 11
// baseline (116.162 us; speedup 1.0000x reference)
//
#include <hip/hip_runtime.h>

#define HW    256
#define PLANE (256*256)
#define MID   2
#define NF    5
#define VTS2  168    // Vt row stride in shorts (160 keys + 8 pad)

typedef float f32x4 __attribute__((ext_vector_type(4)));
typedef short s16x8 __attribute__((ext_vector_type(8)));

__device__ __forceinline__ float hw_exp2(float x) {
#if __has_builtin(__builtin_amdgcn_exp2f)
    return __builtin_amdgcn_exp2f(x);
#else
    float r; asm("v_exp_f32 %0, %1" : "=v"(r) : "v"(x)); return r;
#endif
}

// float -> bf16 bits (RNE), low 16
__device__ __forceinline__ unsigned int f2bf(float f) {
    unsigned int u = __float_as_uint(f);
    u += 0x7FFF + ((u >> 16) & 1);
    return u >> 16;
}

// low = hi16(a), high = hi16(b); one v_perm_b32 (validated R9/R10)
__device__ __forceinline__ unsigned int pack_bf(float a, float b) {
    return __builtin_amdgcn_perm(__float_as_uint(b), __float_as_uint(a), 0x07060302u);
}

__device__ __forceinline__ s16x8 mk_frag4(uint2 lo) {
    union { s16x8 v; unsigned int u[4]; } c;
    c.u[0] = lo.x; c.u[1] = lo.y; c.u[2] = 0; c.u[3] = 0;
    return c.v;
}
__device__ __forceinline__ s16x8 mk_frag8(unsigned int u0, unsigned int u1,
                                          unsigned int u2, unsigned int u3) {
    union { s16x8 v; unsigned int u[4]; } c;
    c.u[0] = u0; c.u[1] = u1; c.u[2] = u2; c.u[3] = u3;
    return c.v;
}

// Kernel 1: 2 blocks per patch (key halves). Block = 4 waves; wave w owns query
// tiles w*5..w*5+4 (5 independent MFMA->exp->MFMA chains, R8-validated layout).
// 5 kb-iters over this block's 160 keys. Writes per-query partials
// (acc0,acc1,acc2,den) to ws[(r*2+h)*320 + tok] as float4.
__global__ __launch_bounds__(256) void attn_partial_mfma(
    const float* __restrict__ in,        // (1,5,3,256,256)
    const float* __restrict__ Wq,
    const float* __restrict__ Wk,
    const float* __restrict__ bq,
    const float* __restrict__ bk,
    const float* __restrict__ bv,
    float* __restrict__ ws)
{
    __shared__ __align__(16) unsigned short Kbf[164 * 4]; // 160 local keys + zero slot @160
    __shared__ __align__(16) unsigned short Qbf[320 * 4];
    __shared__ __align__(16) unsigned short Vt[16 * VTS2]; // [ch][local key]; ch3=1.0, ch4+=0

    const int tid  = threadIdx.x;    // 0..255
    const int w    = tid >> 6;       // wave 0..3
    const int lane = tid & 63;
    const int col  = lane & 15;
    const int quad = lane >> 4;
    const int b    = blockIdx.x;     // 0..2047
    const int r    = b >> 1;         // patch id
    const int h    = b & 1;          // key half
    const int s1   = r >> 5, s2 = r & 31;

    // ---- Vt static rows: row 3 = bf16(1.0), rows 4..15 = 0; K zero slot ----
    {
        unsigned int* v32 = (unsigned int*)Vt;
        for (int idx = 3 * (VTS2 / 2) + tid; idx < 16 * (VTS2 / 2); idx += 256)
            v32[idx] = (idx < 4 * (VTS2 / 2)) ? 0x3F803F80u : 0u;
    }
    if (tid < 4) *(uint2*)&Kbf[(160 + tid) * 4] = make_uint2(0u, 0u);

    const float QS = 0.57735026918962576f * 1.44269504088896340f; // 1/sqrt(3)*log2e
    const float bv0 = bv[0], bv1 = bv[1], bv2 = bv[2];

    // ---- Q staging: all 320 query tokens ----
    for (int t = tid; t < 320; t += 256) {
        const int n = t >> 6, i = t & 63;
        const int pix = (s1 * 8 + (i >> 3)) * HW + s2 * 8 + (i & 7);
        const float x0 = in[(n * 3 + 0) * PLANE + pix];
        const float x1 = in[(n * 3 + 1) * PLANE + pix];
        const float x2 = in[(n * 3 + 2) * PLANE + pix];
        const float q0 = (x0 * Wq[0] + x1 * Wq[1] + x2 * Wq[2] + bq[0]) * QS;
        const float q1 = (x0 * Wq[3] + x1 * Wq[4] + x2 * Wq[5] + bq[1]) * QS;
        const float q2 = (x0 * Wq[6] + x1 * Wq[7] + x2 * Wq[8] + bq[2]) * QS;
        *(uint2*)&Qbf[t * 4] = make_uint2(f2bf(q0) | (f2bf(q1) << 16), f2bf(q2));
    }
    // ---- K/V staging: this block's 160 keys (global tokens h*160 + t) ----
    if (tid < 160) {
        const int g = h * 160 + tid;
        const int n = g >> 6, i = g & 63;
        const int pix = (s1 * 8 + (i >> 3)) * HW + s2 * 8 + (i & 7);
        const float x0 = in[(n * 3 + 0) * PLANE + pix];
        const float x1 = in[(n * 3 + 1) * PLANE + pix];
        const float x2 = in[(n * 3 + 2) * PLANE + pix];
        const float k0 = x0 * Wk[0] + x1 * Wk[1] + x2 * Wk[2] + bk[0];
        const float k1 = x0 * Wk[3] + x1 * Wk[4] + x2 * Wk[5] + bk[1];
        const float k2 = x0 * Wk[6] + x1 * Wk[7] + x2 * Wk[8] + bk[2];
        *(uint2*)&Kbf[tid * 4] = make_uint2(f2bf(k0) | (f2bf(k1) << 16), f2bf(k2));
        Vt[0 * VTS2 + tid] = (unsigned short)f2bf(x0 + bv0);
        Vt[1 * VTS2 + tid] = (unsigned short)f2bf(x1 + bv1);
        Vt[2 * VTS2 + tid] = (unsigned short)f2bf(x2 + bv2);
    }
    __syncthreads();

    // ---- Q fragments for this wave's 5 query tiles ----
    s16x8 qf[5];
#pragma unroll
    for (int u = 0; u < 5; ++u) {
        uint2 qr = *(const uint2*)&Qbf[((w * 5 + u) * 16 + col) * 4];
        if (quad != 0) { qr.x = 0; qr.y = 0; }
        qf[u] = mk_frag4(qr);
    }

    f32x4 acc[5];
#pragma unroll
    for (int u = 0; u < 5; ++u) acc[u] = (f32x4){0.f, 0.f, 0.f, 0.f};
    const f32x4 zero4 = (f32x4){0.f, 0.f, 0.f, 0.f};

    // ---- main loop: 5 key-blocks of 32 (this half's keys) ----
    const bool kz = (quad == 0);
#pragma unroll 2
    for (int kb = 0; kb < 5; ++kb) {
        const int i0 = kz ? (kb * 32 + col) : 160;
        const int i1 = kz ? (kb * 32 + 16 + col) : 160;
        const s16x8 a0 = mk_frag4(*(const uint2*)&Kbf[i0 * 4]);
        const s16x8 a1 = mk_frag4(*(const uint2*)&Kbf[i1 * 4]);
        const unsigned short* vp = &Vt[col * VTS2 + kb * 32 + quad * 4];
        const uint2 vlo = *(const uint2*)vp;         // keys +0..3   -> j0..3
        const uint2 vhi = *(const uint2*)(vp + 16);  // keys +16..19 -> j4..7
        const s16x8 vf = mk_frag8(vlo.x, vlo.y, vhi.x, vhi.y);
#pragma unroll
        for (int u = 0; u < 5; ++u) {
            f32x4 c0 = __builtin_amdgcn_mfma_f32_16x16x32_bf16(a0, qf[u], zero4, 0, 0, 0);
            f32x4 c1 = __builtin_amdgcn_mfma_f32_16x16x32_bf16(a1, qf[u], zero4, 0, 0, 0);
            const unsigned int p0 = pack_bf(hw_exp2(c0[0]), hw_exp2(c0[1]));
            const unsigned int p1 = pack_bf(hw_exp2(c0[2]), hw_exp2(c0[3]));
            const unsigned int p2 = pack_bf(hw_exp2(c1[0]), hw_exp2(c1[1]));
            const unsigned int p3 = pack_bf(hw_exp2(c1[2]), hw_exp2(c1[3]));
            const s16x8 pf = mk_frag8(p0, p1, p2, p3);
            acc[u] = __builtin_amdgcn_mfma_f32_16x16x32_bf16(pf, vf, acc[u], 0, 0, 0);
        }
    }

    // ---- store partials: lane holds D[q = quad*4+rr][ch = col], ch<4 kept ----
    if (col < 4) {
        const int base = b * 320;
#pragma unroll
        for (int u = 0; u < 5; ++u) {
            const int tbase = (w * 5 + u) * 16 + quad * 4;
#pragma unroll
            for (int rr = 0; rr < 4; ++rr)
                ws[(base + tbase + rr) * 4 + col] = acc[u][rr];
        }
    }
}

// Kernel 2: combine halves, outputs, losses, rec image (R6-validated epilogue).
__global__ __launch_bounds__(256) void finalize_kernel(
    const float* __restrict__ outp,
    const float* __restrict__ loss_diff,
    const int*   __restrict__ step,
    const int*   __restrict__ max_steps,
    const float4* __restrict__ ws4,
    float* __restrict__ d_out)           // [0]=loss, [1..196608]=rec_image
{
    const int tid = threadIdx.x;
    const int w   = tid >> 6;
    const int l   = tid & 63;
    const int r   = blockIdx.x * 4 + w;  // grid 256 -> patches 0..1023
    const int s1  = r >> 5, s2 = r & 31;
    const int pix = (s1 * 8 + (l >> 3)) * HW + s2 * 8 + (l & 7);

    float o[NF][3];
#pragma unroll
    for (int j = 0; j < NF; ++j) {
        const float4 pa = ws4[(2 * r)     * 320 + j * 64 + l];
        const float4 pb = ws4[(2 * r + 1) * 320 + j * 64 + l];
        const float inv = 1.0f / (pa.w + pb.w);
        o[j][0] = (pa.x + pb.x) * inv;
        o[j][1] = (pa.y + pb.y) * inv;
        o[j][2] = (pa.z + pb.z) * inv;
    }

    float y[NF][3];
#pragma unroll
    for (int j = 0; j < NF; ++j)
#pragma unroll
        for (int c = 0; c < 3; ++c)
            y[j][c] = outp[(j * 3 + c) * PLANE + pix];

    const float t  = 1.0f - (float)step[0] / (float)max_steps[0];
    const float t2 = t * t, t4 = t2 * t2, t8 = t4 * t4;
    const float coeff = loss_diff[0] * t8 * t2;

    float midp = 0.0f, allp = 0.0f;
#pragma unroll
    for (int j = 0; j < NF; ++j)
#pragma unroll
        for (int c = 0; c < 3; ++c) {
            const float d = y[MID][c] - o[j][c];
            const float e = y[j][c]   - o[j][c];
            midp += d * d;
            allp += e * e;
        }
    float tl = (midp + coeff * allp) * (1.0f / 960.0f);

#pragma unroll
    for (int c = 0; c < 3; ++c) {
        const float rec = 0.2f * (o[0][c] + o[1][c] + o[2][c] + o[3][c] + o[4][c]);
        d_out[1 + c * PLANE + pix] = rec;
        const float dr = y[MID][c] - rec;
        tl += dr * dr * (1.0f / 196608.0f);
    }

#pragma unroll
    for (int off = 32; off; off >>= 1) tl += __shfl_down(tl, off);
    if (l == 0) atomicAdd(d_out, tl);
}

extern "C" void kernel_launch(void* const* d_in, const int* in_sizes, int n_in,
                              void* d_out, int out_size, void* d_ws, size_t ws_size,
                              hipStream_t stream) {
    const float* in        = (const float*)d_in[0];
    const float* outp      = (const float*)d_in[1];
    const float* Wq        = (const float*)d_in[2];
    const float* Wk        = (const float*)d_in[3];
    const float* bq        = (const float*)d_in[4];
    const float* bk        = (const float*)d_in[5];
    const float* bv        = (const float*)d_in[6];
    const float* loss_diff = (const float*)d_in[7];
    const int*   step      = (const int*)d_in[8];
    const int*   max_steps = (const int*)d_in[9];
    float* out = (float*)d_out;
    float* ws  = (float*)d_ws;   // 2048*320*16 B = 10.5 MB, fully overwritten each call

    // loss accumulator must start at 0 (d_out is poisoned before each call)
    hipMemsetAsync(out, 0, sizeof(float), stream);

    attn_partial_mfma<<<2048, 256, 0, stream>>>(in, Wq, Wk, bq, bk, bv, ws);
    finalize_kernel<<<256, 256, 0, stream>>>(outp, loss_diff, step, max_steps,
                                             (const float4*)ws, out);
}

// Round 12
// 99.410 us; speedup vs baseline: 1.1685x; 1.1685x over previous
//
#include <hip/hip_runtime.h>

#define HW    256
#define PLANE (256*256)
#define MID   2
#define NF    5
#define VTS   328     // Vt row stride in shorts (+8 pad: breaks 16-way bank alias)

typedef float f32x4 __attribute__((ext_vector_type(4)));
typedef short s16x8 __attribute__((ext_vector_type(8)));

__device__ __forceinline__ float hw_exp2(float x) {
#if __has_builtin(__builtin_amdgcn_exp2f)
    return __builtin_amdgcn_exp2f(x);
#else
    float r; asm("v_exp_f32 %0, %1" : "=v"(r) : "v"(x)); return r;
#endif
}

// float -> bf16 bits (RNE), result in low 16 bits
__device__ __forceinline__ unsigned int f2bf(float f) {
    unsigned int u = __float_as_uint(f);
    u += 0x7FFF + ((u >> 16) & 1);
    return u >> 16;
}

__device__ __forceinline__ s16x8 mk_frag4(uint2 lo) {   // 4 bf16 + 4 zeros
    union { s16x8 v; unsigned int u[4]; } c;
    c.u[0] = lo.x; c.u[1] = lo.y; c.u[2] = 0; c.u[3] = 0;
    return c.v;
}
__device__ __forceinline__ s16x8 mk_frag8(unsigned int u0, unsigned int u1,
                                          unsigned int u2, unsigned int u3) {
    union { s16x8 v; unsigned int u[4]; } c;
    c.u[0] = u0; c.u[1] = u1; c.u[2] = u2; c.u[3] = u3;
    return c.v;
}

// One block (4 waves) per patch. Wave w owns query-tiles w*5..w*5+4 (16 q each).
// Scores: S'[key][query] via mfma(A=K, B=Q'), dim K padded 3->32.
// P = exp2(S') stays in registers (C layout == PV A layout, m=lane&15=query).
// [acc|den] = P * [V | ones] via mfma(A=P, B=Vt-frag), keys contracted 32/step.
// (R8 structure: best measured — bench 100.1 us; R9/R10/R11 alternatives all
// neutral or regressed. Final kernel.)
__global__ __launch_bounds__(256) void attn_mfma_kernel(
    const float* __restrict__ in,        // (1,5,3,256,256)
    const float* __restrict__ outp,      // (1,5,3,256,256)
    const float* __restrict__ Wq,
    const float* __restrict__ Wk,
    const float* __restrict__ bq,
    const float* __restrict__ bk,
    const float* __restrict__ bv,
    const float* __restrict__ loss_diff,
    const int*   __restrict__ step,
    const int*   __restrict__ max_steps,
    float* __restrict__ d_out)           // [0]=loss, [1..196608]=rec_image
{
    __shared__ __align__(16) unsigned short Kbf[320 * 4]; // [token][dim0..2,0] bf16
    __shared__ __align__(16) unsigned short Qbf[320 * 4];
    __shared__ __align__(16) unsigned short Vt[16 * VTS]; // [ch][token]; ch3=1.0, ch4..15=0
    __shared__ __align__(16) float oLDS[320 * 4];         // [token][acc0,acc1,acc2,den]
    __shared__ float red[4];

    const int tid  = threadIdx.x;    // 0..255
    const int w    = tid >> 6;       // wave 0..3
    const int lane = tid & 63;
    const int col  = lane & 15;      // MFMA n/m index
    const int quad = lane >> 4;
    const int r    = blockIdx.x;     // patch id
    const int s1   = r >> 5, s2 = r & 31;

    // ---- Vt static rows: row 3 = bf16(1.0) pairs, rows 4..15 = 0 ----
    {
        unsigned int* v32 = (unsigned int*)Vt;
        for (int idx = 3 * (VTS / 2) + tid; idx < 16 * (VTS / 2); idx += 256)
            v32[idx] = (idx < 4 * (VTS / 2)) ? 0x3F803F80u : 0u;
    }

    // ---- token staging: K, Q' (scaled), V^T -> bf16 in LDS ----
    const float QS = 0.57735026918962576f * 1.44269504088896340f; // 1/sqrt(3)*log2e
    const float bv0 = bv[0], bv1 = bv[1], bv2 = bv[2];
    for (int t = tid; t < 320; t += 256) {
        const int n = t >> 6, i = t & 63;
        const int pix = (s1 * 8 + (i >> 3)) * HW + s2 * 8 + (i & 7);
        const float x0 = in[(n * 3 + 0) * PLANE + pix];
        const float x1 = in[(n * 3 + 1) * PLANE + pix];
        const float x2 = in[(n * 3 + 2) * PLANE + pix];
        const float k0 = x0 * Wk[0] + x1 * Wk[1] + x2 * Wk[2] + bk[0];
        const float k1 = x0 * Wk[3] + x1 * Wk[4] + x2 * Wk[5] + bk[1];
        const float k2 = x0 * Wk[6] + x1 * Wk[7] + x2 * Wk[8] + bk[2];
        const float q0 = (x0 * Wq[0] + x1 * Wq[1] + x2 * Wq[2] + bq[0]) * QS;
        const float q1 = (x0 * Wq[3] + x1 * Wq[4] + x2 * Wq[5] + bq[1]) * QS;
        const float q2 = (x0 * Wq[6] + x1 * Wq[7] + x2 * Wq[8] + bq[2]) * QS;
        *(uint2*)&Kbf[t * 4] = make_uint2(f2bf(k0) | (f2bf(k1) << 16), f2bf(k2));
        *(uint2*)&Qbf[t * 4] = make_uint2(f2bf(q0) | (f2bf(q1) << 16), f2bf(q2));
        Vt[0 * VTS + t] = (unsigned short)f2bf(x0 + bv0);
        Vt[1 * VTS + t] = (unsigned short)f2bf(x1 + bv1);
        Vt[2 * VTS + t] = (unsigned short)f2bf(x2 + bv2);
    }
    __syncthreads();

    // ---- Q fragments for this wave's 5 query-tiles (dims in quad 0 only) ----
    s16x8 qf[5];
#pragma unroll
    for (int u = 0; u < 5; ++u) {
        uint2 qr = *(const uint2*)&Qbf[((w * 5 + u) * 16 + col) * 4];
        if (quad != 0) { qr.x = 0; qr.y = 0; }
        qf[u] = mk_frag4(qr);
    }

    f32x4 acc[5];
#pragma unroll
    for (int u = 0; u < 5; ++u) acc[u] = (f32x4){0.f, 0.f, 0.f, 0.f};
    const f32x4 zero4 = (f32x4){0.f, 0.f, 0.f, 0.f};

    // ---- main loop over 10 key-blocks of 32 ----
    for (int kb = 0; kb < 10; ++kb) {
        uint2 kr0 = *(const uint2*)&Kbf[(kb * 32 + col) * 4];
        uint2 kr1 = *(const uint2*)&Kbf[(kb * 32 + 16 + col) * 4];
        if (quad != 0) { kr0.x = 0; kr0.y = 0; kr1.x = 0; kr1.y = 0; }
        const s16x8 a0 = mk_frag4(kr0);
        const s16x8 a1 = mk_frag4(kr1);
        // V B-fragment, key permutation matches C->A repack below
        const unsigned short* vp = &Vt[col * VTS + kb * 32 + quad * 4];
        const uint2 vlo = *(const uint2*)vp;          // keys +0..3  -> slots j0..3
        const uint2 vhi = *(const uint2*)(vp + 16);   // keys +16..19 -> slots j4..7
        const s16x8 vf = mk_frag8(vlo.x, vlo.y, vhi.x, vhi.y);
#pragma unroll
        for (int u = 0; u < 5; ++u) {
            f32x4 c0 = __builtin_amdgcn_mfma_f32_16x16x32_bf16(a0, qf[u], zero4, 0, 0, 0);
            f32x4 c1 = __builtin_amdgcn_mfma_f32_16x16x32_bf16(a1, qf[u], zero4, 0, 0, 0);
            // P = exp2(S'), truncate to bf16, pack into PV A-fragment
            const unsigned int p0 = (__float_as_uint(hw_exp2(c0[0])) >> 16) |
                                    (__float_as_uint(hw_exp2(c0[1])) & 0xFFFF0000u);
            const unsigned int p1 = (__float_as_uint(hw_exp2(c0[2])) >> 16) |
                                    (__float_as_uint(hw_exp2(c0[3])) & 0xFFFF0000u);
            const unsigned int p2 = (__float_as_uint(hw_exp2(c1[0])) >> 16) |
                                    (__float_as_uint(hw_exp2(c1[1])) & 0xFFFF0000u);
            const unsigned int p3 = (__float_as_uint(hw_exp2(c1[2])) >> 16) |
                                    (__float_as_uint(hw_exp2(c1[3])) & 0xFFFF0000u);
            const s16x8 pf = mk_frag8(p0, p1, p2, p3);
            acc[u] = __builtin_amdgcn_mfma_f32_16x16x32_bf16(pf, vf, acc[u], 0, 0, 0);
        }
    }

    // ---- write (acc0..2, den) per token to LDS; lane holds D[q=quad*4+rr][ch=col] ----
    if (col < 4) {
#pragma unroll
        for (int u = 0; u < 5; ++u) {
            const int tbase = (w * 5 + u) * 16 + quad * 4;
#pragma unroll
            for (int rr = 0; rr < 4; ++rr)
                oLDS[(tbase + rr) * 4 + col] = acc[u][rr];
        }
    }
    __syncthreads();

    // ---- epilogue: losses + rec image ----
    float tl = 0.0f;
    const float tt = 1.0f - (float)step[0] / (float)max_steps[0];
    const float t2 = tt * tt, t4 = t2 * t2, t8 = t4 * t4;
    const float coeff = loss_diff[0] * t8 * t2;

    for (int t = tid; t < 320; t += 256) {
        const int n = t >> 6, i = t & 63;
        const int pix = (s1 * 8 + (i >> 3)) * HW + s2 * 8 + (i & 7);
        const float4 oa = *(const float4*)&oLDS[t * 4];
        const float inv = 1.0f / oa.w;
        const float o0 = oa.x * inv, o1 = oa.y * inv, o2 = oa.z * inv;
        const float y0  = outp[(n * 3 + 0) * PLANE + pix];
        const float y1  = outp[(n * 3 + 1) * PLANE + pix];
        const float y2  = outp[(n * 3 + 2) * PLANE + pix];
        const float ym0 = outp[(MID * 3 + 0) * PLANE + pix];
        const float ym1 = outp[(MID * 3 + 1) * PLANE + pix];
        const float ym2 = outp[(MID * 3 + 2) * PLANE + pix];
        const float d0 = ym0 - o0, d1 = ym1 - o1, d2 = ym2 - o2;
        const float e0 = y0 - o0,  e1 = y1 - o1,  e2 = y2 - o2;
        tl += (d0*d0 + d1*d1 + d2*d2 + coeff * (e0*e0 + e1*e1 + e2*e2)) * (1.0f / 960.0f);
    }

    if (tid < 192) {
        const int c = tid >> 6, ii = tid & 63;
        const int pix2 = (s1 * 8 + (ii >> 3)) * HW + s2 * 8 + (ii & 7);
        float rec = 0.0f;
#pragma unroll
        for (int n = 0; n < NF; ++n) {
            const int t = n * 64 + ii;
            rec += oLDS[t * 4 + c] / oLDS[t * 4 + 3];
        }
        rec *= 0.2f;
        d_out[1 + c * PLANE + pix2] = rec;
        const float ym = outp[(MID * 3 + c) * PLANE + pix2];
        const float dr = ym - rec;
        tl += dr * dr * (1.0f / 196608.0f);
    }

#pragma unroll
    for (int off = 32; off; off >>= 1) tl += __shfl_down(tl, off);
    if (lane == 0) red[w] = tl;
    __syncthreads();
    if (tid == 0) atomicAdd(d_out, red[0] + red[1] + red[2] + red[3]);
}

extern "C" void kernel_launch(void* const* d_in, const int* in_sizes, int n_in,
                              void* d_out, int out_size, void* d_ws, size_t ws_size,
                              hipStream_t stream) {
    const float* in        = (const float*)d_in[0];
    const float* outp      = (const float*)d_in[1];
    const float* Wq        = (const float*)d_in[2];
    const float* Wk        = (const float*)d_in[3];
    const float* bq        = (const float*)d_in[4];
    const float* bk        = (const float*)d_in[5];
    const float* bv        = (const float*)d_in[6];
    const float* loss_diff = (const float*)d_in[7];
    const int*   step      = (const int*)d_in[8];
    const int*   max_steps = (const int*)d_in[9];
    float* out = (float*)d_out;

    // loss accumulator must start at 0 (d_out is poisoned before each call)
    hipMemsetAsync(out, 0, sizeof(float), stream);

    attn_mfma_kernel<<<1024, 256, 0, stream>>>(
        in, outp, Wq, Wk, bq, bk, bv, loss_diff, step, max_steps, out);
}